// Round 4
// baseline (443.225 us; speedup 1.0000x reference)
//
#include <hip/hip_runtime.h>
#include <cfloat>

#define CC 512   // K (input channels)
#define EE 128   // embedding cols
#define NTH 256  // 4 waves per block
#define RPW 16   // rows per wave
#define RPB 64   // rows per block
#define NBLK 2048 // 131072 / 64   (64 rows/block; 4096 rows/batch = 64 blocks/batch, no batch straddle)

typedef _Float16 half8 __attribute__((ext_vector_type(8)));
typedef float floatx4 __attribute__((ext_vector_type(4)));

__device__ __forceinline__ void ins_top(float v, float& t0, float& t1, float& t2) {
  float m  = fminf(t0, v); t0 = fmaxf(t0, v);
  float m2 = fminf(t1, m); t1 = fmaxf(t1, m);
  t2 = fmaxf(t2, m2);
}
__device__ __forceinline__ void ins_bot(float v, float& b0, float& b1, float& b2) {
  float M  = fmaxf(b0, v); b0 = fminf(b0, v);
  float M2 = fmaxf(b1, M); b1 = fminf(b1, M);
  b2 = fminf(b2, M2);
}

// Prologue: W[k][n] f32 -> Wt[n][k] f16 (fragment-native, 128 KB, L2-resident).
// Writes coalesced (consecutive t -> consecutive k0); reads L2-absorbed (W=256KB).
__global__ __launch_bounds__(256)
void convert_w(const float* __restrict__ w, _Float16* __restrict__ wt) {
  int t = blockIdx.x * 256 + threadIdx.x;  // 8192 threads
  int n  = t >> 6;          // 0..127
  int k0 = (t & 63) * 8;    // 0..504
  half8 h;
  #pragma unroll
  for (int j = 0; j < 8; ++j)
    h[j] = (_Float16)w[(size_t)(k0 + j) * EE + n];
  *(half8*)(wt + (size_t)n * CC + k0) = h;
}

// Fused GEMM (f16 MFMA) + top3/bot3 partials. NO LDS / NO barriers in K-loop:
// A fragments stream from HBM (distance-2 register prefetch);
// B fragments load straight from Wt in L1/L2 (64B-contiguous per q-quad,
// same 8KB/K-step shared by all waves on the CU -> L1 broadcast).
__global__ __launch_bounds__(NTH, 4)
void weldon_main(const float* __restrict__ x, const _Float16* __restrict__ wt,
                 float* __restrict__ part) {
  __shared__ float scr[4][EE][6];  // epilogue merge scratch, 12 KB

  const int tid  = threadIdx.x;
  const int lane = tid & 63, wid = tid >> 6;
  const int q = lane >> 4, r = lane & 15;

  const size_t row = (size_t)blockIdx.x * RPB + wid * RPW + r;  // A row for this lane
  const float*    ap = x  + row * CC + q * 8;
  const _Float16* bp = wt + (size_t)r * CC + q * 8;  // + ct*16*CC + ks*32

  floatx4 acc[8];
  const floatx4 zero = {0.f, 0.f, 0.f, 0.f};
  #pragma unroll
  for (int j = 0; j < 8; ++j) acc[j] = zero;

  float4 buf[3][2];  // distance-2 A prefetch ring
  buf[0][0] = *(const float4*)(ap);       buf[0][1] = *(const float4*)(ap + 4);
  buf[1][0] = *(const float4*)(ap + 32);  buf[1][1] = *(const float4*)(ap + 36);

  #pragma unroll
  for (int ks = 0; ks < 16; ++ks) {
    const int cur = ks % 3;
    if (ks < 14) {
      const int pf = (ks + 2) % 3;
      buf[pf][0] = *(const float4*)(ap + (ks + 2) * 32);
      buf[pf][1] = *(const float4*)(ap + (ks + 2) * 32 + 4);
    }
    half8 a;
    {
      float4 v0 = buf[cur][0], v1 = buf[cur][1];
      a[0] = (_Float16)v0.x; a[1] = (_Float16)v0.y;
      a[2] = (_Float16)v0.z; a[3] = (_Float16)v0.w;
      a[4] = (_Float16)v1.x; a[5] = (_Float16)v1.y;
      a[6] = (_Float16)v1.z; a[7] = (_Float16)v1.w;
    }
    #pragma unroll
    for (int ct = 0; ct < 8; ++ct) {
      half8 b = *(const half8*)(bp + (size_t)ct * 16 * CC + ks * 32);
      acc[ct] = __builtin_amdgcn_mfma_f32_16x16x32_f16(a, b, acc[ct], 0, 0, 0);
    }
  }

  // Epilogue. C/D layout (R0/R3-verified): col = ct*16 + r, row(m) = q*4 + g.
  #pragma unroll
  for (int ct = 0; ct < 8; ++ct) {
    float t0 = -FLT_MAX, t1 = -FLT_MAX, t2 = -FLT_MAX;
    float b0 =  FLT_MAX, b1 =  FLT_MAX, b2 =  FLT_MAX;
    #pragma unroll
    for (int g = 0; g < 4; ++g) {
      float v = acc[ct][g];
      ins_top(v, t0, t1, t2);
      ins_bot(v, b0, b1, b2);
    }
    #pragma unroll
    for (int mask = 16; mask <= 32; mask <<= 1) {  // merge the 4 q-groups (16 rows)
      float o0 = __shfl_xor(t0, mask), o1 = __shfl_xor(t1, mask), o2 = __shfl_xor(t2, mask);
      ins_top(o0, t0, t1, t2); ins_top(o1, t0, t1, t2); ins_top(o2, t0, t1, t2);
      float p0 = __shfl_xor(b0, mask), p1 = __shfl_xor(b1, mask), p2 = __shfl_xor(b2, mask);
      ins_bot(p0, b0, b1, b2); ins_bot(p1, b0, b1, b2); ins_bot(p2, b0, b1, b2);
    }
    if (q == (ct >> 1)) {  // one writer quad per ct
      float* p = scr[wid][ct * 16 + r];
      p[0] = t0; p[1] = t1; p[2] = t2; p[3] = b0; p[4] = b1; p[5] = b2;
    }
  }
  __syncthreads();

  if (tid < EE) {  // merge 4 waves -> block partial for column tid
    float t0 = -FLT_MAX, t1 = -FLT_MAX, t2 = -FLT_MAX;
    float b0 =  FLT_MAX, b1 =  FLT_MAX, b2 =  FLT_MAX;
    #pragma unroll
    for (int wv = 0; wv < 4; ++wv) {
      const float* p = scr[wv][tid];
      ins_top(p[0], t0, t1, t2); ins_top(p[1], t0, t1, t2); ins_top(p[2], t0, t1, t2);
      ins_bot(p[3], b0, b1, b2); ins_bot(p[4], b0, b1, b2); ins_bot(p[5], b0, b1, b2);
    }
    float* p = part + ((size_t)blockIdx.x * EE + tid) * 6;
    p[0] = t0; p[1] = t1; p[2] = t2; p[3] = b0; p[4] = b1; p[5] = b2;
  }
}

// Merge 64 block-partials per (b,e), pool, L2-normalize per b.
__global__ __launch_bounds__(128)
void weldon_merge(const float* __restrict__ part, float* __restrict__ out) {
  const int b = blockIdx.x;   // 0..31
  const int e = threadIdx.x;  // 0..127
  float t0 = -FLT_MAX, t1 = -FLT_MAX, t2 = -FLT_MAX;
  float b0 =  FLT_MAX, b1 =  FLT_MAX, b2 =  FLT_MAX;
  for (int c = 0; c < 64; ++c) {
    const float* p = part + ((size_t)((b * 64 + c) * EE + e)) * 6;
    ins_top(p[0], t0, t1, t2); ins_top(p[1], t0, t1, t2); ins_top(p[2], t0, t1, t2);
    ins_bot(p[3], b0, b1, b2); ins_bot(p[4], b0, b1, b2); ins_bot(p[5], b0, b1, b2);
  }
  float pooled = t0 + t1 + t2 + b0 + b1 + b2;
  float sq = pooled * pooled;
  #pragma unroll
  for (int m = 1; m < 64; m <<= 1) sq += __shfl_xor(sq, m, 64);
  __shared__ float red[2];
  if ((e & 63) == 0) red[e >> 6] = sq;
  __syncthreads();
  float total = red[0] + red[1];
  out[b * EE + e] = pooled * rsqrtf(fmaxf(total, 1e-12f));
}

extern "C" void kernel_launch(void* const* d_in, const int* in_sizes, int n_in,
                              void* d_out, int out_size, void* d_ws, size_t ws_size,
                              hipStream_t stream) {
  const float* x = (const float*)d_in[0];  // [32,64,64,512] fp32
  const float* w = (const float*)d_in[1];  // [512,128] fp32
  float* out = (float*)d_out;              // [32,128] fp32

  _Float16* wt  = (_Float16*)d_ws;                 // 128 KB f16 W^T
  float*    part = (float*)d_ws + 32768;           // 2048*128*6 floats = 6.29 MB

  convert_w <<<dim3(32),   dim3(256), 0, stream>>>(w, wt);
  weldon_main<<<dim3(NBLK), dim3(NTH), 0, stream>>>(x, wt, part);
  weldon_merge<<<dim3(32), dim3(128), 0, stream>>>(part, out);
}

// Round 5
// 402.737 us; speedup vs baseline: 1.1005x; 1.1005x over previous
//
#include <hip/hip_runtime.h>
#include <cfloat>

#define CC 512    // K (input channels)
#define EE 128    // embedding cols
#define NTH 256   // 4 waves per block
#define RPB 128   // rows per block (8 m-tiles of 16)
#define MT  8     // m-tiles per block
#define NBLK 1024 // 131072 / 128  (32 blocks per batch, no batch straddle)
#define DEPTH 4   // A-prefetch ring depth (K-steps)

typedef _Float16 half8 __attribute__((ext_vector_type(8)));
typedef float floatx4 __attribute__((ext_vector_type(4)));

__device__ __forceinline__ void ins_top(float v, float& t0, float& t1, float& t2) {
  float m  = fminf(t0, v); t0 = fmaxf(t0, v);
  float m2 = fminf(t1, m); t1 = fmaxf(t1, m);
  t2 = fmaxf(t2, m2);
}
__device__ __forceinline__ void ins_bot(float v, float& b0, float& b1, float& b2) {
  float M  = fmaxf(b0, v); b0 = fminf(b0, v);
  float M2 = fmaxf(b1, M); b1 = fminf(b1, M);
  b2 = fminf(b2, M2);
}

// Prologue: W[k][n] f32 -> Wt[n][k] f16 (fragment-native, 128 KB, L2-resident).
__global__ __launch_bounds__(256)
void convert_w(const float* __restrict__ w, _Float16* __restrict__ wt) {
  int t = blockIdx.x * 256 + threadIdx.x;  // 8192 threads
  int n  = t >> 6;          // 0..127
  int k0 = (t & 63) * 8;    // 0..504
  half8 h;
  #pragma unroll
  for (int j = 0; j < 8; ++j)
    h[j] = (_Float16)w[(size_t)(k0 + j) * EE + n];
  *(half8*)(wt + (size_t)n * CC + k0) = h;
}

// Fused GEMM (f16 MFMA) + top3/bot3. B lives ENTIRELY in registers (128 VGPRs/lane),
// so the K-loop's only vmem is the A-stream -> vmcnt prefetch ring actually works.
// No LDS, no __syncthreads anywhere.
__global__ __launch_bounds__(NTH, 2)
void weldon_main(const float* __restrict__ x, const _Float16* __restrict__ wt,
                 float* __restrict__ part) {
  const int tid  = threadIdx.x;
  const int lane = tid & 63, wid = tid >> 6;   // wave owns cols [wid*32, wid*32+32)
  const int q = lane >> 4, r = lane & 15;

  // --- Preload B fragments: ct = wid*2 + c; frag = Wt[(ct*16+r)][ks*32 + q*8 ..+8]
  half8 b[2][16];
  #pragma unroll
  for (int c = 0; c < 2; ++c) {
    const _Float16* bp = wt + (size_t)((wid * 2 + c) * 16 + r) * CC + q * 8;
    #pragma unroll
    for (int ks = 0; ks < 16; ++ks)
      b[c][ks] = *(const half8*)(bp + ks * 32);
  }

  const size_t rbase = (size_t)blockIdx.x * RPB;
  const float* ap = x + (rbase + r) * CC + q * 8;
  // flattened step s in [0,128): row = rbase + (s>>4)*16 + r, cols (s&15)*32 + q*8

  float4 buf[DEPTH][2];
  #pragma unroll
  for (int s = 0; s < DEPTH; ++s) {
    const float* p = ap + (size_t)((s >> 4) * (16 * CC) + (s & 15) * 32);
    buf[s][0] = *(const float4*)(p);
    buf[s][1] = *(const float4*)(p + 4);
  }

  float tk[2][6];  // running top3 / bot3 per owned ct
  #pragma unroll
  for (int c = 0; c < 2; ++c) {
    tk[c][0] = tk[c][1] = tk[c][2] = -FLT_MAX;
    tk[c][3] = tk[c][4] = tk[c][5] =  FLT_MAX;
  }

  const floatx4 zero = {0.f, 0.f, 0.f, 0.f};
  for (int mt = 0; mt < MT; ++mt) {
    floatx4 acc0 = zero, acc1 = zero;
    #pragma unroll
    for (int ks = 0; ks < 16; ++ks) {
      const int s = mt * 16 + ks;
      const int slot = s & (DEPTH - 1);
      half8 a;
      {
        float4 v0 = buf[slot][0], v1 = buf[slot][1];
        a[0] = (_Float16)v0.x; a[1] = (_Float16)v0.y;
        a[2] = (_Float16)v0.z; a[3] = (_Float16)v0.w;
        a[4] = (_Float16)v1.x; a[5] = (_Float16)v1.y;
        a[6] = (_Float16)v1.z; a[7] = (_Float16)v1.w;
      }
      const int sn = s + DEPTH;
      if (sn < MT * 16) {  // refill the slot we just consumed
        const float* p = ap + (size_t)((sn >> 4) * (16 * CC) + (sn & 15) * 32);
        buf[slot][0] = *(const float4*)(p);
        buf[slot][1] = *(const float4*)(p + 4);
      }
      acc0 = __builtin_amdgcn_mfma_f32_16x16x32_f16(a, b[0][ks], acc0, 0, 0, 0);
      acc1 = __builtin_amdgcn_mfma_f32_16x16x32_f16(a, b[1][ks], acc1, 0, 0, 0);
    }
    // C/D layout (verified R0-R4): col = ct*16 + r, local row = q*4 + g.
    #pragma unroll
    for (int g = 0; g < 4; ++g) {
      ins_top(acc0[g], tk[0][0], tk[0][1], tk[0][2]);
      ins_bot(acc0[g], tk[0][3], tk[0][4], tk[0][5]);
      ins_top(acc1[g], tk[1][0], tk[1][1], tk[1][2]);
      ins_bot(acc1[g], tk[1][3], tk[1][4], tk[1][5]);
    }
  }

  // Merge the 4 q-groups (same col r, disjoint row subsets) via shuffles.
  #pragma unroll
  for (int c = 0; c < 2; ++c) {
    #pragma unroll
    for (int mask = 16; mask <= 32; mask <<= 1) {
      float o0 = __shfl_xor(tk[c][0], mask), o1 = __shfl_xor(tk[c][1], mask), o2 = __shfl_xor(tk[c][2], mask);
      ins_top(o0, tk[c][0], tk[c][1], tk[c][2]);
      ins_top(o1, tk[c][0], tk[c][1], tk[c][2]);
      ins_top(o2, tk[c][0], tk[c][1], tk[c][2]);
      float p0 = __shfl_xor(tk[c][3], mask), p1 = __shfl_xor(tk[c][4], mask), p2 = __shfl_xor(tk[c][5], mask);
      ins_bot(p0, tk[c][3], tk[c][4], tk[c][5]);
      ins_bot(p1, tk[c][3], tk[c][4], tk[c][5]);
      ins_bot(p2, tk[c][3], tk[c][4], tk[c][5]);
    }
    if (q == c) {  // one writer quad per ct; cols are wave-exclusive -> no LDS merge
      float* p = part + ((size_t)blockIdx.x * EE + (wid * 2 + c) * 16 + r) * 6;
      p[0] = tk[c][0]; p[1] = tk[c][1]; p[2] = tk[c][2];
      p[3] = tk[c][3]; p[4] = tk[c][4]; p[5] = tk[c][5];
    }
  }
}

// Merge 32 block-partials per (b,e), pool, L2-normalize per b.
__global__ __launch_bounds__(128)
void weldon_merge(const float* __restrict__ part, float* __restrict__ out) {
  const int b = blockIdx.x;   // 0..31
  const int e = threadIdx.x;  // 0..127
  float t0 = -FLT_MAX, t1 = -FLT_MAX, t2 = -FLT_MAX;
  float b0 =  FLT_MAX, b1 =  FLT_MAX, b2 =  FLT_MAX;
  #pragma unroll
  for (int c = 0; c < 32; ++c) {
    const float* p = part + ((size_t)((b * 32 + c) * EE + e)) * 6;
    ins_top(p[0], t0, t1, t2); ins_top(p[1], t0, t1, t2); ins_top(p[2], t0, t1, t2);
    ins_bot(p[3], b0, b1, b2); ins_bot(p[4], b0, b1, b2); ins_bot(p[5], b0, b1, b2);
  }
  float pooled = t0 + t1 + t2 + b0 + b1 + b2;
  float sq = pooled * pooled;
  #pragma unroll
  for (int m = 1; m < 64; m <<= 1) sq += __shfl_xor(sq, m, 64);
  __shared__ float red[2];
  if ((e & 63) == 0) red[e >> 6] = sq;
  __syncthreads();
  float total = red[0] + red[1];
  out[b * EE + e] = pooled * rsqrtf(fmaxf(total, 1e-12f));
}

extern "C" void kernel_launch(void* const* d_in, const int* in_sizes, int n_in,
                              void* d_out, int out_size, void* d_ws, size_t ws_size,
                              hipStream_t stream) {
  const float* x = (const float*)d_in[0];  // [32,64,64,512] fp32
  const float* w = (const float*)d_in[1];  // [512,128] fp32
  float* out = (float*)d_out;              // [32,128] fp32

  _Float16* wt   = (_Float16*)d_ws;        // 128 KB f16 W^T
  float*    part = (float*)d_ws + 32768;   // 1024*128*6 floats = 3.1 MB

  convert_w  <<<dim3(32),   dim3(256), 0, stream>>>(w, wt);
  weldon_main<<<dim3(NBLK), dim3(NTH), 0, stream>>>(x, wt, part);
  weldon_merge<<<dim3(32),  dim3(128), 0, stream>>>(part, out);
}